// Round 14
// baseline (315.516 us; speedup 1.0000x reference)
//
#include <hip/hip_runtime.h>

#define T_SEQ 4096
#define H_NUM 12
#define HD    64
#define C_DIM 768
#define N_QKV 2304
#define HT    (T_SEQ * HD)   // per-head elements = 262144
#define KT_TOT (T_SEQ / 64)  // 64 k-tiles, walked sequentially (cumsum order!)

typedef float    f32x4 __attribute__((ext_vector_type(4)));
typedef float    f32x2 __attribute__((ext_vector_type(2)));
typedef _Float16 half8 __attribute__((ext_vector_type(8)));
typedef _Float16 half4 __attribute__((ext_vector_type(4)));
typedef _Float16 half2v __attribute__((ext_vector_type(2)));
typedef __fp16   fp16x2 __attribute__((ext_vector_type(2)));
typedef unsigned uint4v __attribute__((ext_vector_type(4)));

// async global->LDS, 16B/lane, dest = wave-uniform base + lane*16
#define GLDS(gp, lp) __builtin_amdgcn_global_load_lds( \
    (const __attribute__((address_space(1))) void*)(gp), \
    (__attribute__((address_space(3))) void*)(lp), 16, 0, 0)

// dual-update lane swaps (gfx950): a'[32:63]=b[0:31], b'[0:31]=a[32:63]
// Used ONLY for the two-register pk transpose (verified R4-R6/R9/R11/R13).
// SESSION LEDGER of failed directions (do not retry without new evidence):
//  - R2: __launch_bounds__(256,5) -> VGPR cap 102 -> scratch spill, 4.5x slower
//  - R3: split-K over blockIdx.z -> max(cumsum,1e-6) clamp chaos -> FAIL
//  - R5: s_setprio around MFMA in barrier-locked waves -> priority inversion
//  - R7: __shfl_xor emulation via permlane-self-swap -> carry corruption FAIL
//  - R9: attn pipeline w/ vf read-ahead -> +64 VGPR, occupancy loss, 163->176us
//  - R10: attn pipeline w/ staggered DMA + JIT V-reads -> marginal FAIL (491520)
//  - R12: gemm_qkv 128x128 tile -> 64KB LDS, 2 blocks/CU + tail imbalance -> -30us
// R14: gemm_proj rewritten in the VERIFIED qkv structure (GLDS staging, 64x64
// tile, 3 blocks/CU) with W_proj pre-converted to f16 [n][k] ONCE (split_wp)
// instead of fp32-load+convert 64x redundantly. Per-acc-element MFMA call
// sequence unchanged -> output bitwise identical (absmax must stay 131072.0).
__device__ __forceinline__ void permlane32_swap(unsigned& a, unsigned& b) {
    asm("v_permlane32_swap_b32 %0, %1" : "+v"(a), "+v"(b));
}
// a[16:31]<->b[0:15], a[48:63]<->b[32:47]
__device__ __forceinline__ void permlane16_swap(unsigned& a, unsigned& b) {
    asm("v_permlane16_swap_b32 %0, %1" : "+v"(a), "+v"(b));
}

// ---------------------------------------------------------------------------
// split x (fp32) -> xhi + xlo (f16 planes)
// ---------------------------------------------------------------------------
__global__ __launch_bounds__(256) void split_x_kernel(
    const float* __restrict__ x, _Float16* __restrict__ xh,
    _Float16* __restrict__ xl, int n4)
{
    const int i = blockIdx.x * 256 + threadIdx.x;
    if (i >= n4) return;
    const float4 v = ((const float4*)x)[i];
    const float vv[4] = {v.x, v.y, v.z, v.w};
    half4 h, l;
    #pragma unroll
    for (int j = 0; j < 4; ++j) {
        const _Float16 hh = (_Float16)vv[j];
        h[j] = hh;
        l[j] = (_Float16)(vv[j] - (float)hh);
    }
    ((half4*)xh)[i] = h;
    ((half4*)xl)[i] = l;
}

// ---------------------------------------------------------------------------
// transpose+split w_attn [768][2304] -> wthi/wtlo [2304][768] (f16)
// ---------------------------------------------------------------------------
__global__ __launch_bounds__(256) void split_wt_kernel(
    const float* __restrict__ W, _Float16* __restrict__ wth,
    _Float16* __restrict__ wtl)
{
    __shared__ float Ws[64][65];
    const int tid = threadIdx.x;
    const int n0 = blockIdx.x * 64, k0 = blockIdx.y * 64;
    const int lr = tid >> 4, lc = (tid & 15) << 2;
    #pragma unroll
    for (int i = 0; i < 4; ++i) {
        const float4 v = *(const float4*)(W + (size_t)(k0 + lr + i * 16) * N_QKV + n0 + lc);
        Ws[lr + i * 16][lc + 0] = v.x; Ws[lr + i * 16][lc + 1] = v.y;
        Ws[lr + i * 16][lc + 2] = v.z; Ws[lr + i * 16][lc + 3] = v.w;
    }
    __syncthreads();
    const int n = tid >> 2, ks = (tid & 3) << 4;
    half8 h0, h1, l0, l1;
    #pragma unroll
    for (int j = 0; j < 8; ++j) {
        const float v = Ws[ks + j][n];
        const _Float16 hh = (_Float16)v;
        h0[j] = hh; l0[j] = (_Float16)(v - (float)hh);
    }
    #pragma unroll
    for (int j = 0; j < 8; ++j) {
        const float v = Ws[ks + 8 + j][n];
        const _Float16 hh = (_Float16)v;
        h1[j] = hh; l1[j] = (_Float16)(v - (float)hh);
    }
    const size_t dst = (size_t)(n0 + n) * C_DIM + k0 + ks;
    *(half8*)(wth + dst) = h0; *(half8*)(wth + dst + 8) = h1;
    *(half8*)(wtl + dst) = l0; *(half8*)(wtl + dst + 8) = l1;
}

// ---------------------------------------------------------------------------
// transpose+convert w_proj [768][768] -> wpt [n][k] f16 (single plane).
// Same f32->f16 RNE cast the old gemm_proj did in-kernel 64x redundantly.
// ---------------------------------------------------------------------------
__global__ __launch_bounds__(256) void split_wp_kernel(
    const float* __restrict__ W, _Float16* __restrict__ wpt)
{
    __shared__ float Ws[64][65];
    const int tid = threadIdx.x;
    const int n0 = blockIdx.x * 64, k0 = blockIdx.y * 64;
    const int lr = tid >> 4, lc = (tid & 15) << 2;
    #pragma unroll
    for (int i = 0; i < 4; ++i) {
        const float4 v = *(const float4*)(W + (size_t)(k0 + lr + i * 16) * C_DIM + n0 + lc);
        Ws[lr + i * 16][lc + 0] = v.x; Ws[lr + i * 16][lc + 1] = v.y;
        Ws[lr + i * 16][lc + 2] = v.z; Ws[lr + i * 16][lc + 3] = v.w;
    }
    __syncthreads();
    const int n = tid >> 2, ks = (tid & 3) << 4;
    half8 h0, h1;
    #pragma unroll
    for (int j = 0; j < 8; ++j) h0[j] = (_Float16)Ws[ks + j][n];
    #pragma unroll
    for (int j = 0; j < 8; ++j) h1[j] = (_Float16)Ws[ks + 8 + j][n];
    const size_t dst = (size_t)(n0 + n) * C_DIM + k0 + ks;
    *(half8*)(wpt + dst) = h0; *(half8*)(wpt + dst + 8) = h1;
}

// ---------------------------------------------------------------------------
// QKV GEMM via split-f16 MFMA: [4096,768]x[768,2304] in 3 terms
// (AhBh + AhBl + AlBh), fp32 acc. 128m x 64n tile, BK=64, 256 thr, 48KB LDS,
// 3 blocks/CU (R12 showed 128n/64KB/2-blocks regresses -30us).
// ---------------------------------------------------------------------------
__global__ __launch_bounds__(256) void gemm_qkv_kernel(
    const _Float16* __restrict__ xh, const _Float16* __restrict__ xl,
    const _Float16* __restrict__ wth, const _Float16* __restrict__ wtl,
    const float* __restrict__ bias,
    _Float16* __restrict__ qhi, _Float16* __restrict__ qlo,
    _Float16* __restrict__ khi, _Float16* __restrict__ klo,
    _Float16* __restrict__ vt)
{
    __shared__ __align__(16) _Float16 AH[128 * 64];
    __shared__ __align__(16) _Float16 AL[128 * 64];
    __shared__ __align__(16) _Float16 BH[64 * 64];
    __shared__ __align__(16) _Float16 BL[64 * 64];
    const int tid = threadIdx.x;
    const int wv = tid >> 6, lane = tid & 63;
    const int fm = lane & 15, fg = lane >> 4;
    const int lrow = lane >> 3;
    const int lcs  = (lane & 7) ^ (lrow & 7);   // swizzled source chunk
    const int bx = blockIdx.x;                  // n-tile (0..35)
    const int m0 = blockIdx.y * 128;

    auto dma_chunk = [&](int c) {
        const int kc0 = c * 64;
        #pragma unroll
        for (int i = 0; i < 12; ++i) {
            const int qidx = wv * 12 + i;
            if (qidx < 16) {
                const int rg = qidx;
                GLDS(xh + (size_t)(m0 + rg * 8 + lrow) * C_DIM + kc0 + lcs * 8, &AH[rg * 512]);
            } else if (qidx < 32) {
                const int rg = qidx - 16;
                GLDS(xl + (size_t)(m0 + rg * 8 + lrow) * C_DIM + kc0 + lcs * 8, &AL[rg * 512]);
            } else if (qidx < 40) {
                const int rg = qidx - 32;
                GLDS(wth + (size_t)(bx * 64 + rg * 8 + lrow) * C_DIM + kc0 + lcs * 8, &BH[rg * 512]);
            } else {
                const int rg = qidx - 40;
                GLDS(wtl + (size_t)(bx * 64 + rg * 8 + lrow) * C_DIM + kc0 + lcs * 8, &BL[rg * 512]);
            }
        }
    };

    f32x4 acc[2][4];
    #pragma unroll
    for (int mt = 0; mt < 2; ++mt)
        #pragma unroll
        for (int ct = 0; ct < 4; ++ct) acc[mt][ct] = (f32x4){0.f, 0.f, 0.f, 0.f};

    const int swz = fm & 7;
    dma_chunk(0);
    #pragma unroll 1
    for (int c = 0; c < C_DIM / 64; ++c) {
        __syncthreads();   // staged chunk c visible (drains DMA vmcnt)
        half8 ah[2][2], al[2][2], bh[4][2], bl[4][2];
        #pragma unroll
        for (int mt = 0; mt < 2; ++mt) {
            const int rb = (wv * 32 + mt * 16 + fm) * 64;
            #pragma unroll
            for (int kc = 0; kc < 2; ++kc) {
                const int cb = ((kc * 4 + fg) ^ swz) * 8;
                ah[mt][kc] = *(const half8*)&AH[rb + cb];
                al[mt][kc] = *(const half8*)&AL[rb + cb];
            }
        }
        #pragma unroll
        for (int ct = 0; ct < 4; ++ct) {
            const int rb = (ct * 16 + fm) * 64;
            #pragma unroll
            for (int kc = 0; kc < 2; ++kc) {
                const int cb = ((kc * 4 + fg) ^ swz) * 8;
                bh[ct][kc] = *(const half8*)&BH[rb + cb];
                bl[ct][kc] = *(const half8*)&BL[rb + cb];
            }
        }
        __syncthreads();   // all waves done reading staging
        if (c + 1 < C_DIM / 64) dma_chunk(c + 1);   // overlaps with MFMAs below
        #pragma unroll
        for (int mt = 0; mt < 2; ++mt)
            #pragma unroll
            for (int ct = 0; ct < 4; ++ct)
                #pragma unroll
                for (int kc = 0; kc < 2; ++kc) {
                    acc[mt][ct] = __builtin_amdgcn_mfma_f32_16x16x32_f16(ah[mt][kc], bh[ct][kc], acc[mt][ct], 0, 0, 0);
                    acc[mt][ct] = __builtin_amdgcn_mfma_f32_16x16x32_f16(ah[mt][kc], bl[ct][kc], acc[mt][ct], 0, 0, 0);
                    acc[mt][ct] = __builtin_amdgcn_mfma_f32_16x16x32_f16(al[mt][kc], bh[ct][kc], acc[mt][ct], 0, 0, 0);
                }
    }

    const int sec = bx / 12, h = bx % 12;
    const size_t hb = (size_t)h * HT;
    float bb[4];
    #pragma unroll
    for (int ct = 0; ct < 4; ++ct) bb[ct] = bias[bx * 64 + ct * 16 + fm];

    if (sec < 2) {
        _Float16* dh = (sec == 0) ? qhi : khi;
        _Float16* dl = (sec == 0) ? qlo : klo;
        #pragma unroll
        for (int mt = 0; mt < 2; ++mt)
            #pragma unroll
            for (int r = 0; r < 4; ++r) {
                float o[4];
                float ss = 0.f;
                #pragma unroll
                for (int ct = 0; ct < 4; ++ct) {
                    o[ct] = acc[mt][ct][r] + bb[ct];
                    ss += o[ct] * o[ct];
                }
                #pragma unroll
                for (int mk = 1; mk < 16; mk <<= 1) ss += __shfl_xor(ss, mk, 16);
                const float invn = 1.0f / fmaxf(sqrtf(ss), 1e-12f);
                const int t = m0 + wv * 32 + mt * 16 + fg * 4 + r;
                const size_t rb = hb + (size_t)t * HD;
                #pragma unroll
                for (int ct = 0; ct < 4; ++ct) {
                    const float v = o[ct] * invn;
                    const _Float16 vh = (_Float16)v;
                    dh[rb + ct * 16 + fm] = vh;
                    dl[rb + ct * 16 + fm] = (_Float16)(v - (float)vh);
                }
            }
    } else {
        #pragma unroll
        for (int mt = 0; mt < 2; ++mt) {
            const int t0 = m0 + wv * 32 + mt * 16 + fg * 4;
            #pragma unroll
            for (int ct = 0; ct < 4; ++ct) {
                half4 pk;
                #pragma unroll
                for (int r = 0; r < 4; ++r) pk[r] = (_Float16)(acc[mt][ct][r] + bb[ct]);
                *(half4*)(vt + hb + (size_t)(ct * 16 + fm) * T_SEQ + t0) = pk;
            }
        }
    }
}

// ---------------------------------------------------------------------------
// Fused attention. 256 thr / 4 waves; wave wv owns q-rows [wv*16, wv*16+16).
// Sequential k-walk over all 64 tiles (cumsum order == reference order; do
// NOT split-K: the 1e-6 denominator clamp amplifies any reordered summation
// chaotically — split-K failed correctness on codegen-dependent rounding).
// K hi/lo + V double-buffered in LDS via swizzled global_load_lds:
// one barrier per tile; next-tile DMA issued BEFORE frag reads so its
// latency hides under frag reads + full tile compute.
// DMA addressing is INCREMENTAL; scan uses float2 PACKED ops (bitwise-
// identical); serial carry chain scalar in original order (numerics!).
// STRUCTURAL LIMIT (R4-R12 evidence): latency-bound on the serial
// QK^T->scan->PV chain; occupancy grid-capped (768 blocks = 3/CU exactly);
// cross-tile pipelining tried 3 ways (R7/R9/R10) — closed.
// ---------------------------------------------------------------------------
__global__ __launch_bounds__(256) void attn_kernel(
    const _Float16* __restrict__ qhi, const _Float16* __restrict__ qlo,
    const _Float16* __restrict__ khi, const _Float16* __restrict__ klo,
    const _Float16* __restrict__ vt,  _Float16* __restrict__ ylin)
{
    __shared__ __align__(16) _Float16 KH[2][64 * 64];
    __shared__ __align__(16) _Float16 KL[2][64 * 64];
    __shared__ __align__(16) _Float16 VS[2][64 * 64];

    const int tid = threadIdx.x;
    const int wv = tid >> 6, lane = tid & 63;
    const int fm = lane & 15, fg = lane >> 4;
    const int lrow = lane >> 3;
    const int lcs  = (lane & 7) ^ (lrow & 7);
    const int h = blockIdx.y, qt = blockIdx.x;
    const size_t hb = (size_t)h * HT;

    // Q B-frags, fixed for whole block
    const int q = qt * 64 + wv * 16 + fm;
    half8 qf[2][2];
    #pragma unroll
    for (int kc = 0; kc < 2; ++kc) {
        const size_t off = hb + (size_t)q * HD + kc * 32 + fg * 8;
        qf[0][kc] = *(const half8*)(qhi + off);
        qf[1][kc] = *(const half8*)(qlo + off);
    }

    // ---- hoisted DMA descriptors: per wave, 6 streams, incremental addrs ----
    const _Float16* ga[6];   // global source (advances by stride per tile)
    _Float16*       lb[6];   // LDS dest in buf0 (buf1 = +4096 elements)
    int             gstr[6]; // per-tile element stride
    #pragma unroll
    for (int i = 0; i < 6; ++i) {
        const int qidx = wv * 6 + i;
        const int rg = qidx & 7;
        if (qidx < 8) {
            ga[i] = khi + hb + (size_t)(rg * 8 + lrow) * HD + lcs * 8;
            lb[i] = &KH[0][rg * 512];
            gstr[i] = 64 * HD;
        } else if (qidx < 16) {
            ga[i] = klo + hb + (size_t)(rg * 8 + lrow) * HD + lcs * 8;
            lb[i] = &KL[0][rg * 512];
            gstr[i] = 64 * HD;
        } else {
            ga[i] = vt + hb + (size_t)(rg * 8 + lrow) * T_SEQ + lcs * 8;
            lb[i] = &VS[0][rg * 512];
            gstr[i] = 64;
        }
    }
    auto issue_tiles = [&](int bufoff) {   // issues current addrs, then advances
        #pragma unroll
        for (int i = 0; i < 6; ++i) {
            GLDS(ga[i], lb[i] + bufoff);
            ga[i] += gstr[i];
        }
    };

    f32x4 yacc[4];
    #pragma unroll
    for (int ct = 0; ct < 4; ++ct) yacc[ct] = (f32x4){0.f, 0.f, 0.f, 0.f};
    float carry = 0.0f;
    const int swz = fm & 7;

    issue_tiles(0);   // tile 0 -> buf 0
    #pragma unroll 1
    for (int kt = 0; kt < KT_TOT; ++kt) {
        const int cur = kt & 1;
        __syncthreads();   // buf[cur] DMA drained; prior reads of buf[cur^1] done
        if (kt + 1 < KT_TOT) issue_tiles((cur ^ 1) * 4096);   // hides under compute

        half8 ka[4][2], kl[4][2], vf[4][2];
        #pragma unroll
        for (int kr = 0; kr < 4; ++kr) {
            const int rb = (kr * 16 + fm) * 64;
            #pragma unroll
            for (int kc = 0; kc < 2; ++kc) {
                const int cb = ((kc * 4 + fg) ^ swz) * 8;
                ka[kr][kc] = *(const half8*)&KH[cur][rb + cb];
                kl[kr][kc] = *(const half8*)&KL[cur][rb + cb];
            }
        }
        #pragma unroll
        for (int ct = 0; ct < 4; ++ct) {
            const int rb = (ct * 16 + fm) * 64;
            #pragma unroll
            for (int kc = 0; kc < 2; ++kc)
                vf[ct][kc] = *(const half8*)&VS[cur][rb + (((kc * 4 + fg) ^ swz) * 8)];
        }

        // S^T = K.Q^T (split-f16, fp32 acc)
        f32x4 sacc[4];
        #pragma unroll
        for (int kr = 0; kr < 4; ++kr) sacc[kr] = (f32x4){0.f, 0.f, 0.f, 0.f};
        #pragma unroll
        for (int kr = 0; kr < 4; ++kr)
            #pragma unroll
            for (int kc = 0; kc < 2; ++kc) {
                sacc[kr] = __builtin_amdgcn_mfma_f32_16x16x32_f16(ka[kr][kc], qf[0][kc], sacc[kr], 0, 0, 0);
                sacc[kr] = __builtin_amdgcn_mfma_f32_16x16x32_f16(ka[kr][kc], qf[1][kc], sacc[kr], 0, 0, 0);
                sacc[kr] = __builtin_amdgcn_mfma_f32_16x16x32_f16(kl[kr][kc], qf[0][kc], sacc[kr], 0, 0, 0);
            }

        // scan: kr-pairs processed with packed float2 ops (bitwise-identical
        // to scalar: same operand pairs, same order). Serial carry chain
        // (pref/base/carry) stays scalar in original order.
        unsigned pk[4][2];
        #pragma unroll
        for (int pr = 0; pr < 2; ++pr) {
            const int kra = 2 * pr, krb = 2 * pr + 1;
            const f32x2 S0 = {sacc[kra][0], sacc[krb][0]};
            const f32x2 S1 = {sacc[kra][1], sacc[krb][1]};
            const f32x2 S2 = {sacc[kra][2], sacc[krb][2]};
            const f32x2 S3 = {sacc[kra][3], sacc[krb][3]};
            const f32x2 P1 = S0 + S1;
            const f32x2 P2 = P1 + S2;
            const f32x2 P3 = P2 + S3;
            f32x2 U1;
            U1[0] = __shfl_xor(P3[0], 16, 64);
            U1[1] = __shfl_xor(P3[1], 16, 64);
            const f32x2 PAIR = P3 + U1;
            f32x2 U2;
            U2[0] = __shfl_xor(PAIR[0], 32, 64);
            U2[1] = __shfl_xor(PAIR[1], 32, 64);
            const f32x2 TOT = PAIR + U2;
            #pragma unroll
            for (int qq = 0; qq < 2; ++qq) {
                const int kr = 2 * pr + qq;
                const float pref = ((fg & 1) ? U1[qq] : 0.0f) + ((fg & 2) ? U2[qq] : 0.0f);
                const float base = carry + pref;
                carry += TOT[qq];
                const f32x2 b2 = {base, base};
                const f32x2 d01 = b2 + (f32x2){S0[qq], P1[qq]};
                const f32x2 d23 = b2 + (f32x2){P2[qq], P3[qq]};
                const f32x2 eps = {1e-6f, 1e-6f};
                const f32x2 m01 = __builtin_elementwise_max(d01, eps);
                const f32x2 m23 = __builtin_elementwise_max(d23, eps);
                const f32x2 r01 = {__builtin_amdgcn_rcpf(m01[0]), __builtin_amdgcn_rcpf(m01[1])};
                const f32x2 r23 = {__builtin_amdgcn_rcpf(m23[0]), __builtin_amdgcn_rcpf(m23[1])};
                const f32x2 n01 = {S0[qq], S1[qq]};
                const f32x2 n23 = {S2[qq], S3[qq]};
                const f32x2 sc = {0.03125f, 0.03125f};
                const f32x2 a01 = (n01 * r01) * sc;
                const f32x2 a23 = (n23 * r23) * sc;
                const fp16x2 c0 = __builtin_amdgcn_cvt_pkrtz(a01[0], a01[1]);
                const fp16x2 c1 = __builtin_amdgcn_cvt_pkrtz(a23[0], a23[1]);
                pk[kr][0] = __builtin_bit_cast(unsigned, c0);
                pk[kr][1] = __builtin_bit_cast(unsigned, c1);
            }
        }

        // lane-reg transpose: sacc C-layout -> PV A-frag layout, in-register.
        #pragma unroll
        for (int g = 0; g < 2; ++g)
            #pragma unroll
            for (int hh = 0; hh < 2; ++hh) {
                permlane32_swap(pk[g * 2 + 0][hh], pk[g * 2 + 1][hh]);
                permlane16_swap(pk[g * 2 + 0][hh], pk[g * 2 + 1][hh]);
            }

        // Y += att @ V
        #pragma unroll
        for (int kc = 0; kc < 2; ++kc) {
            const uint4v u = {pk[2 * kc][0], pk[2 * kc][1],
                              pk[2 * kc + 1][0], pk[2 * kc + 1][1]};
            const half8 af = __builtin_bit_cast(half8, u);
            #pragma unroll
            for (int ct = 0; ct < 4; ++ct)
                yacc[ct] = __builtin_amdgcn_mfma_f32_16x16x32_f16(af, vf[ct][kc], yacc[ct], 0, 0, 0);
        }
    }

    // epilogue: ylin f16 = y * 2^-12 (acc holds y*2^-5 -> scale 2^-7)
    #pragma unroll
    for (int ct = 0; ct < 4; ++ct)
        #pragma unroll
        for (int r = 0; r < 4; ++r) {
            const int t = qt * 64 + wv * 16 + fg * 4 + r;
            ylin[(size_t)t * C_DIM + h * HD + ct * 16 + fm] =
                (_Float16)(yacc[ct][r] * 0.0078125f);
        }
}

// ---------------------------------------------------------------------------
// Proj GEMM, qkv-style: ylin(f16,*2^-12)[4096,768] @ wpt^T -> out fp32.
// 64m x 64n tile, BK=64, GLDS staging w/ XOR chunk swizzle, 16KB LDS,
// grid 64x12 = 768 blocks = 3/CU exactly. Per-acc-element MFMA sequence
// (kt asc, kc 0->1, same K=32 ranges, same f16 inputs) identical to the
// old fp32-W version -> bitwise-identical output.
// ---------------------------------------------------------------------------
__global__ __launch_bounds__(256) void gemm_proj_kernel(
    const _Float16* __restrict__ A, const _Float16* __restrict__ wpt,
    const float* __restrict__ bias, float* __restrict__ out)
{
    __shared__ __align__(16) _Float16 AS[64 * 64];
    __shared__ __align__(16) _Float16 BS[64 * 64];
    const int tid = threadIdx.x;
    const int wv = tid >> 6, lane = tid & 63;
    const int fm = lane & 15, fg = lane >> 4;
    const int lrow = lane >> 3;
    const int lcs  = (lane & 7) ^ (lrow & 7);
    const int m0 = blockIdx.x * 64, n0 = blockIdx.y * 64;

    auto dma_chunk = [&](int c) {
        const int kc0 = c * 64;
        #pragma unroll
        for (int i = 0; i < 4; ++i) {
            const int qidx = wv * 4 + i;
            if (qidx < 8) {
                const int rg = qidx;
                GLDS(A + (size_t)(m0 + rg * 8 + lrow) * C_DIM + kc0 + lcs * 8, &AS[rg * 512]);
            } else {
                const int rg = qidx - 8;
                GLDS(wpt + (size_t)(n0 + rg * 8 + lrow) * C_DIM + kc0 + lcs * 8, &BS[rg * 512]);
            }
        }
    };

    f32x4 acc[4];
    #pragma unroll
    for (int ct = 0; ct < 4; ++ct) acc[ct] = (f32x4){0.f, 0.f, 0.f, 0.f};

    const int swz = fm & 7;
    dma_chunk(0);
    #pragma unroll 1
    for (int c = 0; c < C_DIM / 64; ++c) {
        __syncthreads();   // staged chunk c visible (drains DMA vmcnt)
        half8 a[2], b[4][2];
        {
            const int rb = (wv * 16 + fm) * 64;
            #pragma unroll
            for (int kc = 0; kc < 2; ++kc)
                a[kc] = *(const half8*)&AS[rb + (((kc * 4 + fg) ^ swz) * 8)];
        }
        #pragma unroll
        for (int ct = 0; ct < 4; ++ct) {
            const int rb = (ct * 16 + fm) * 64;
            #pragma unroll
            for (int kc = 0; kc < 2; ++kc)
                b[ct][kc] = *(const half8*)&BS[rb + (((kc * 4 + fg) ^ swz) * 8)];
        }
        __syncthreads();   // all waves done reading staging
        if (c + 1 < C_DIM / 64) dma_chunk(c + 1);   // overlaps with MFMAs below
        #pragma unroll
        for (int kc = 0; kc < 2; ++kc)
            #pragma unroll
            for (int ct = 0; ct < 4; ++ct)
                acc[ct] = __builtin_amdgcn_mfma_f32_16x16x32_f16(a[kc], b[ct][kc], acc[ct], 0, 0, 0);
    }
    #pragma unroll
    for (int ct = 0; ct < 4; ++ct)
        #pragma unroll
        for (int r = 0; r < 4; ++r) {
            const int t = m0 + wv * 16 + fg * 4 + r;
            const int n = n0 + ct * 16 + fm;
            out[(size_t)t * C_DIM + n] = acc[ct][r] * 4096.0f + bias[n];
        }
}

extern "C" void kernel_launch(void* const* d_in, const int* in_sizes, int n_in,
                              void* d_out, int out_size, void* d_ws, size_t ws_size,
                              hipStream_t stream)
{
    const float* x      = (const float*)d_in[0];
    const float* w_attn = (const float*)d_in[1];
    const float* b_attn = (const float*)d_in[2];
    const float* w_proj = (const float*)d_in[3];
    const float* b_proj = (const float*)d_in[4];
    float* out = (float*)d_out;

    const size_t perQK = (size_t)H_NUM * HT;      // 3,145,728
    const size_t perX  = (size_t)T_SEQ * C_DIM;   // 3,145,728
    const size_t perW  = (size_t)N_QKV * C_DIM;   // 1,769,472
    _Float16* base = (_Float16*)d_ws;
    _Float16* xhi  = base;
    _Float16* xlo  = xhi + perX;
    _Float16* wthi = xlo + perX;
    _Float16* wtlo = wthi + perW;
    _Float16* qhi  = wtlo + perW;
    _Float16* qlo  = qhi + perQK;
    _Float16* khi  = qlo + perQK;
    _Float16* klo  = khi + perQK;
    _Float16* vtp  = klo + perQK;
    _Float16* ylin = xhi;    // reuse: xhi dead after qkv
    _Float16* wpt  = wtlo;   // reuse: wtlo dead after qkv (needs 768*768 < perW)

    split_x_kernel<<<(perX / 4 + 255) / 256, 256, 0, stream>>>(x, xhi, xlo, perX / 4);
    split_wt_kernel<<<dim3(N_QKV / 64, C_DIM / 64), 256, 0, stream>>>(w_attn, wthi, wtlo);
    gemm_qkv_kernel<<<dim3(N_QKV / 64, T_SEQ / 128), 256, 0, stream>>>(
        xhi, xlo, wthi, wtlo, b_attn, qhi, qlo, khi, klo, vtp);
    split_wp_kernel<<<dim3(C_DIM / 64, C_DIM / 64), 256, 0, stream>>>(w_proj, wpt);
    attn_kernel<<<dim3(T_SEQ / 64, H_NUM), 256, 0, stream>>>(
        qhi, qlo, khi, klo, vtp, ylin);
    gemm_proj_kernel<<<dim3(T_SEQ / 64, C_DIM / 64), 256, 0, stream>>>(
        ylin, wpt, b_proj, out);
}

// Round 15
// 296.471 us; speedup vs baseline: 1.0642x; 1.0642x over previous
//
#include <hip/hip_runtime.h>

#define T_SEQ 4096
#define H_NUM 12
#define HD    64
#define C_DIM 768
#define N_QKV 2304
#define HT    (T_SEQ * HD)   // per-head elements = 262144
#define KT_TOT (T_SEQ / 64)  // 64 k-tiles, walked sequentially (cumsum order!)

typedef float    f32x4 __attribute__((ext_vector_type(4)));
typedef float    f32x2 __attribute__((ext_vector_type(2)));
typedef _Float16 half8 __attribute__((ext_vector_type(8)));
typedef _Float16 half4 __attribute__((ext_vector_type(4)));
typedef _Float16 half2v __attribute__((ext_vector_type(2)));
typedef __fp16   fp16x2 __attribute__((ext_vector_type(2)));
typedef unsigned uint4v __attribute__((ext_vector_type(4)));

// async global->LDS, 16B/lane, dest = wave-uniform base + lane*16
#define GLDS(gp, lp) __builtin_amdgcn_global_load_lds( \
    (const __attribute__((address_space(1))) void*)(gp), \
    (__attribute__((address_space(3))) void*)(lp), 16, 0, 0)

// dual-update lane swaps (gfx950): a'[32:63]=b[0:31], b'[0:31]=a[32:63]
// Used ONLY for the two-register pk transpose (verified R4-R6/R9/R11/R13).
// FINAL SESSION LEDGER (do not retry without new evidence):
//  - R2: __launch_bounds__(256,5) -> VGPR cap 102 -> scratch spill, 4.5x slower
//  - R3: split-K over blockIdx.z -> max(cumsum,1e-6) clamp chaos -> FAIL
//  - R5: s_setprio around MFMA in barrier-locked waves -> priority inversion
//  - R7: __shfl_xor emulation via permlane-self-swap -> carry corruption FAIL
//  - R9: attn pipeline w/ vf read-ahead -> +64 VGPR, occupancy loss, 163->176us
//  - R10: attn pipeline w/ staggered DMA + JIT V-reads -> marginal FAIL (491520)
//  - R12: gemm_qkv 128x128 tile -> 64KB LDS, 2 blocks/CU + tail -> -30us
//  - R14: proj rewrite + split_wp -> within noise, extra launch; reverted
// Session: 360.7 -> 296.5us (-18%). attn pinned at ~163us by the serial
// QK^T->scan->PV chain (reordering forbidden by 1e-6 clamp chaos) at 3
// blocks/CU (split-K forbidden). Numerical-ordering floor, not HW roofline.
__device__ __forceinline__ void permlane32_swap(unsigned& a, unsigned& b) {
    asm("v_permlane32_swap_b32 %0, %1" : "+v"(a), "+v"(b));
}
// a[16:31]<->b[0:15], a[48:63]<->b[32:47]
__device__ __forceinline__ void permlane16_swap(unsigned& a, unsigned& b) {
    asm("v_permlane16_swap_b32 %0, %1" : "+v"(a), "+v"(b));
}

// ---------------------------------------------------------------------------
// split x (fp32) -> xhi + xlo (f16 planes)
// ---------------------------------------------------------------------------
__global__ __launch_bounds__(256) void split_x_kernel(
    const float* __restrict__ x, _Float16* __restrict__ xh,
    _Float16* __restrict__ xl, int n4)
{
    const int i = blockIdx.x * 256 + threadIdx.x;
    if (i >= n4) return;
    const float4 v = ((const float4*)x)[i];
    const float vv[4] = {v.x, v.y, v.z, v.w};
    half4 h, l;
    #pragma unroll
    for (int j = 0; j < 4; ++j) {
        const _Float16 hh = (_Float16)vv[j];
        h[j] = hh;
        l[j] = (_Float16)(vv[j] - (float)hh);
    }
    ((half4*)xh)[i] = h;
    ((half4*)xl)[i] = l;
}

// ---------------------------------------------------------------------------
// transpose+split w_attn [768][2304] -> wthi/wtlo [2304][768] (f16)
// ---------------------------------------------------------------------------
__global__ __launch_bounds__(256) void split_wt_kernel(
    const float* __restrict__ W, _Float16* __restrict__ wth,
    _Float16* __restrict__ wtl)
{
    __shared__ float Ws[64][65];
    const int tid = threadIdx.x;
    const int n0 = blockIdx.x * 64, k0 = blockIdx.y * 64;
    const int lr = tid >> 4, lc = (tid & 15) << 2;
    #pragma unroll
    for (int i = 0; i < 4; ++i) {
        const float4 v = *(const float4*)(W + (size_t)(k0 + lr + i * 16) * N_QKV + n0 + lc);
        Ws[lr + i * 16][lc + 0] = v.x; Ws[lr + i * 16][lc + 1] = v.y;
        Ws[lr + i * 16][lc + 2] = v.z; Ws[lr + i * 16][lc + 3] = v.w;
    }
    __syncthreads();
    const int n = tid >> 2, ks = (tid & 3) << 4;
    half8 h0, h1, l0, l1;
    #pragma unroll
    for (int j = 0; j < 8; ++j) {
        const float v = Ws[ks + j][n];
        const _Float16 hh = (_Float16)v;
        h0[j] = hh; l0[j] = (_Float16)(v - (float)hh);
    }
    #pragma unroll
    for (int j = 0; j < 8; ++j) {
        const float v = Ws[ks + 8 + j][n];
        const _Float16 hh = (_Float16)v;
        h1[j] = hh; l1[j] = (_Float16)(v - (float)hh);
    }
    const size_t dst = (size_t)(n0 + n) * C_DIM + k0 + ks;
    *(half8*)(wth + dst) = h0; *(half8*)(wth + dst + 8) = h1;
    *(half8*)(wtl + dst) = l0; *(half8*)(wtl + dst + 8) = l1;
}

// ---------------------------------------------------------------------------
// QKV GEMM via split-f16 MFMA: [4096,768]x[768,2304] in 3 terms
// (AhBh + AhBl + AlBh), fp32 acc. 128m x 64n tile, BK=64, 256 thr, 48KB LDS,
// 3 blocks/CU (R12 showed 128n/64KB/2-blocks regresses -30us).
// LDS staged via global_load_lds with XOR chunk swizzle; epilogue fuses
// bias + l2norm + hi/lo split (q,k) or bias + V transpose (v).
// ---------------------------------------------------------------------------
__global__ __launch_bounds__(256) void gemm_qkv_kernel(
    const _Float16* __restrict__ xh, const _Float16* __restrict__ xl,
    const _Float16* __restrict__ wth, const _Float16* __restrict__ wtl,
    const float* __restrict__ bias,
    _Float16* __restrict__ qhi, _Float16* __restrict__ qlo,
    _Float16* __restrict__ khi, _Float16* __restrict__ klo,
    _Float16* __restrict__ vt)
{
    __shared__ __align__(16) _Float16 AH[128 * 64];
    __shared__ __align__(16) _Float16 AL[128 * 64];
    __shared__ __align__(16) _Float16 BH[64 * 64];
    __shared__ __align__(16) _Float16 BL[64 * 64];
    const int tid = threadIdx.x;
    const int wv = tid >> 6, lane = tid & 63;
    const int fm = lane & 15, fg = lane >> 4;
    const int lrow = lane >> 3;
    const int lcs  = (lane & 7) ^ (lrow & 7);   // swizzled source chunk
    const int bx = blockIdx.x;                  // n-tile (0..35)
    const int m0 = blockIdx.y * 128;

    auto dma_chunk = [&](int c) {
        const int kc0 = c * 64;
        #pragma unroll
        for (int i = 0; i < 12; ++i) {
            const int qidx = wv * 12 + i;
            if (qidx < 16) {
                const int rg = qidx;
                GLDS(xh + (size_t)(m0 + rg * 8 + lrow) * C_DIM + kc0 + lcs * 8, &AH[rg * 512]);
            } else if (qidx < 32) {
                const int rg = qidx - 16;
                GLDS(xl + (size_t)(m0 + rg * 8 + lrow) * C_DIM + kc0 + lcs * 8, &AL[rg * 512]);
            } else if (qidx < 40) {
                const int rg = qidx - 32;
                GLDS(wth + (size_t)(bx * 64 + rg * 8 + lrow) * C_DIM + kc0 + lcs * 8, &BH[rg * 512]);
            } else {
                const int rg = qidx - 40;
                GLDS(wtl + (size_t)(bx * 64 + rg * 8 + lrow) * C_DIM + kc0 + lcs * 8, &BL[rg * 512]);
            }
        }
    };

    f32x4 acc[2][4];
    #pragma unroll
    for (int mt = 0; mt < 2; ++mt)
        #pragma unroll
        for (int ct = 0; ct < 4; ++ct) acc[mt][ct] = (f32x4){0.f, 0.f, 0.f, 0.f};

    const int swz = fm & 7;
    dma_chunk(0);
    #pragma unroll 1
    for (int c = 0; c < C_DIM / 64; ++c) {
        __syncthreads();   // staged chunk c visible (drains DMA vmcnt)
        half8 ah[2][2], al[2][2], bh[4][2], bl[4][2];
        #pragma unroll
        for (int mt = 0; mt < 2; ++mt) {
            const int rb = (wv * 32 + mt * 16 + fm) * 64;
            #pragma unroll
            for (int kc = 0; kc < 2; ++kc) {
                const int cb = ((kc * 4 + fg) ^ swz) * 8;
                ah[mt][kc] = *(const half8*)&AH[rb + cb];
                al[mt][kc] = *(const half8*)&AL[rb + cb];
            }
        }
        #pragma unroll
        for (int ct = 0; ct < 4; ++ct) {
            const int rb = (ct * 16 + fm) * 64;
            #pragma unroll
            for (int kc = 0; kc < 2; ++kc) {
                const int cb = ((kc * 4 + fg) ^ swz) * 8;
                bh[ct][kc] = *(const half8*)&BH[rb + cb];
                bl[ct][kc] = *(const half8*)&BL[rb + cb];
            }
        }
        __syncthreads();   // all waves done reading staging
        if (c + 1 < C_DIM / 64) dma_chunk(c + 1);   // overlaps with MFMAs below
        #pragma unroll
        for (int mt = 0; mt < 2; ++mt)
            #pragma unroll
            for (int ct = 0; ct < 4; ++ct)
                #pragma unroll
                for (int kc = 0; kc < 2; ++kc) {
                    acc[mt][ct] = __builtin_amdgcn_mfma_f32_16x16x32_f16(ah[mt][kc], bh[ct][kc], acc[mt][ct], 0, 0, 0);
                    acc[mt][ct] = __builtin_amdgcn_mfma_f32_16x16x32_f16(ah[mt][kc], bl[ct][kc], acc[mt][ct], 0, 0, 0);
                    acc[mt][ct] = __builtin_amdgcn_mfma_f32_16x16x32_f16(al[mt][kc], bh[ct][kc], acc[mt][ct], 0, 0, 0);
                }
    }

    const int sec = bx / 12, h = bx % 12;
    const size_t hb = (size_t)h * HT;
    float bb[4];
    #pragma unroll
    for (int ct = 0; ct < 4; ++ct) bb[ct] = bias[bx * 64 + ct * 16 + fm];

    if (sec < 2) {
        _Float16* dh = (sec == 0) ? qhi : khi;
        _Float16* dl = (sec == 0) ? qlo : klo;
        #pragma unroll
        for (int mt = 0; mt < 2; ++mt)
            #pragma unroll
            for (int r = 0; r < 4; ++r) {
                float o[4];
                float ss = 0.f;
                #pragma unroll
                for (int ct = 0; ct < 4; ++ct) {
                    o[ct] = acc[mt][ct][r] + bb[ct];
                    ss += o[ct] * o[ct];
                }
                #pragma unroll
                for (int mk = 1; mk < 16; mk <<= 1) ss += __shfl_xor(ss, mk, 16);
                const float invn = 1.0f / fmaxf(sqrtf(ss), 1e-12f);
                const int t = m0 + wv * 32 + mt * 16 + fg * 4 + r;
                const size_t rb = hb + (size_t)t * HD;
                #pragma unroll
                for (int ct = 0; ct < 4; ++ct) {
                    const float v = o[ct] * invn;
                    const _Float16 vh = (_Float16)v;
                    dh[rb + ct * 16 + fm] = vh;
                    dl[rb + ct * 16 + fm] = (_Float16)(v - (float)vh);
                }
            }
    } else {
        #pragma unroll
        for (int mt = 0; mt < 2; ++mt) {
            const int t0 = m0 + wv * 32 + mt * 16 + fg * 4;
            #pragma unroll
            for (int ct = 0; ct < 4; ++ct) {
                half4 pk;
                #pragma unroll
                for (int r = 0; r < 4; ++r) pk[r] = (_Float16)(acc[mt][ct][r] + bb[ct]);
                *(half4*)(vt + hb + (size_t)(ct * 16 + fm) * T_SEQ + t0) = pk;
            }
        }
    }
}

// ---------------------------------------------------------------------------
// Fused attention. 256 thr / 4 waves; wave wv owns q-rows [wv*16, wv*16+16).
// Sequential k-walk over all 64 tiles (cumsum order == reference order; do
// NOT split-K: the 1e-6 denominator clamp amplifies any reordered summation
// chaotically — split-K failed correctness on codegen-dependent rounding).
// K hi/lo + V double-buffered in LDS via swizzled global_load_lds:
// one barrier per tile; next-tile DMA issued BEFORE frag reads so its
// latency hides under frag reads + full tile compute.
// DMA addressing is INCREMENTAL; scan uses float2 PACKED ops (bitwise-
// identical); serial carry chain scalar in original order (numerics!).
// STRUCTURAL LIMIT (R4-R14 evidence): latency-bound on the serial
// QK^T->scan->PV chain; occupancy grid-capped (768 blocks = 3/CU exactly);
// cross-tile pipelining tried 3 ways (R7/R9/R10) — closed.
// ---------------------------------------------------------------------------
__global__ __launch_bounds__(256) void attn_kernel(
    const _Float16* __restrict__ qhi, const _Float16* __restrict__ qlo,
    const _Float16* __restrict__ khi, const _Float16* __restrict__ klo,
    const _Float16* __restrict__ vt,  _Float16* __restrict__ ylin)
{
    __shared__ __align__(16) _Float16 KH[2][64 * 64];
    __shared__ __align__(16) _Float16 KL[2][64 * 64];
    __shared__ __align__(16) _Float16 VS[2][64 * 64];

    const int tid = threadIdx.x;
    const int wv = tid >> 6, lane = tid & 63;
    const int fm = lane & 15, fg = lane >> 4;
    const int lrow = lane >> 3;
    const int lcs  = (lane & 7) ^ (lrow & 7);
    const int h = blockIdx.y, qt = blockIdx.x;
    const size_t hb = (size_t)h * HT;

    // Q B-frags, fixed for whole block
    const int q = qt * 64 + wv * 16 + fm;
    half8 qf[2][2];
    #pragma unroll
    for (int kc = 0; kc < 2; ++kc) {
        const size_t off = hb + (size_t)q * HD + kc * 32 + fg * 8;
        qf[0][kc] = *(const half8*)(qhi + off);
        qf[1][kc] = *(const half8*)(qlo + off);
    }

    // ---- hoisted DMA descriptors: per wave, 6 streams, incremental addrs ----
    const _Float16* ga[6];   // global source (advances by stride per tile)
    _Float16*       lb[6];   // LDS dest in buf0 (buf1 = +4096 elements)
    int             gstr[6]; // per-tile element stride
    #pragma unroll
    for (int i = 0; i < 6; ++i) {
        const int qidx = wv * 6 + i;
        const int rg = qidx & 7;
        if (qidx < 8) {
            ga[i] = khi + hb + (size_t)(rg * 8 + lrow) * HD + lcs * 8;
            lb[i] = &KH[0][rg * 512];
            gstr[i] = 64 * HD;
        } else if (qidx < 16) {
            ga[i] = klo + hb + (size_t)(rg * 8 + lrow) * HD + lcs * 8;
            lb[i] = &KL[0][rg * 512];
            gstr[i] = 64 * HD;
        } else {
            ga[i] = vt + hb + (size_t)(rg * 8 + lrow) * T_SEQ + lcs * 8;
            lb[i] = &VS[0][rg * 512];
            gstr[i] = 64;
        }
    }
    auto issue_tiles = [&](int bufoff) {   // issues current addrs, then advances
        #pragma unroll
        for (int i = 0; i < 6; ++i) {
            GLDS(ga[i], lb[i] + bufoff);
            ga[i] += gstr[i];
        }
    };

    f32x4 yacc[4];
    #pragma unroll
    for (int ct = 0; ct < 4; ++ct) yacc[ct] = (f32x4){0.f, 0.f, 0.f, 0.f};
    float carry = 0.0f;
    const int swz = fm & 7;

    issue_tiles(0);   // tile 0 -> buf 0
    #pragma unroll 1
    for (int kt = 0; kt < KT_TOT; ++kt) {
        const int cur = kt & 1;
        __syncthreads();   // buf[cur] DMA drained; prior reads of buf[cur^1] done
        if (kt + 1 < KT_TOT) issue_tiles((cur ^ 1) * 4096);   // hides under compute

        half8 ka[4][2], kl[4][2], vf[4][2];
        #pragma unroll
        for (int kr = 0; kr < 4; ++kr) {
            const int rb = (kr * 16 + fm) * 64;
            #pragma unroll
            for (int kc = 0; kc < 2; ++kc) {
                const int cb = ((kc * 4 + fg) ^ swz) * 8;
                ka[kr][kc] = *(const half8*)&KH[cur][rb + cb];
                kl[kr][kc] = *(const half8*)&KL[cur][rb + cb];
            }
        }
        #pragma unroll
        for (int ct = 0; ct < 4; ++ct) {
            const int rb = (ct * 16 + fm) * 64;
            #pragma unroll
            for (int kc = 0; kc < 2; ++kc)
                vf[ct][kc] = *(const half8*)&VS[cur][rb + (((kc * 4 + fg) ^ swz) * 8)];
        }

        // S^T = K.Q^T (split-f16, fp32 acc)
        f32x4 sacc[4];
        #pragma unroll
        for (int kr = 0; kr < 4; ++kr) sacc[kr] = (f32x4){0.f, 0.f, 0.f, 0.f};
        #pragma unroll
        for (int kr = 0; kr < 4; ++kr)
            #pragma unroll
            for (int kc = 0; kc < 2; ++kc) {
                sacc[kr] = __builtin_amdgcn_mfma_f32_16x16x32_f16(ka[kr][kc], qf[0][kc], sacc[kr], 0, 0, 0);
                sacc[kr] = __builtin_amdgcn_mfma_f32_16x16x32_f16(ka[kr][kc], qf[1][kc], sacc[kr], 0, 0, 0);
                sacc[kr] = __builtin_amdgcn_mfma_f32_16x16x32_f16(kl[kr][kc], qf[0][kc], sacc[kr], 0, 0, 0);
            }

        // scan: kr-pairs processed with packed float2 ops (bitwise-identical
        // to scalar: same operand pairs, same order). Serial carry chain
        // (pref/base/carry) stays scalar in original order.
        unsigned pk[4][2];
        #pragma unroll
        for (int pr = 0; pr < 2; ++pr) {
            const int kra = 2 * pr, krb = 2 * pr + 1;
            const f32x2 S0 = {sacc[kra][0], sacc[krb][0]};
            const f32x2 S1 = {sacc[kra][1], sacc[krb][1]};
            const f32x2 S2 = {sacc[kra][2], sacc[krb][2]};
            const f32x2 S3 = {sacc[kra][3], sacc[krb][3]};
            const f32x2 P1 = S0 + S1;
            const f32x2 P2 = P1 + S2;
            const f32x2 P3 = P2 + S3;
            f32x2 U1;
            U1[0] = __shfl_xor(P3[0], 16, 64);
            U1[1] = __shfl_xor(P3[1], 16, 64);
            const f32x2 PAIR = P3 + U1;
            f32x2 U2;
            U2[0] = __shfl_xor(PAIR[0], 32, 64);
            U2[1] = __shfl_xor(PAIR[1], 32, 64);
            const f32x2 TOT = PAIR + U2;
            #pragma unroll
            for (int qq = 0; qq < 2; ++qq) {
                const int kr = 2 * pr + qq;
                const float pref = ((fg & 1) ? U1[qq] : 0.0f) + ((fg & 2) ? U2[qq] : 0.0f);
                const float base = carry + pref;
                carry += TOT[qq];
                const f32x2 b2 = {base, base};
                const f32x2 d01 = b2 + (f32x2){S0[qq], P1[qq]};
                const f32x2 d23 = b2 + (f32x2){P2[qq], P3[qq]};
                const f32x2 eps = {1e-6f, 1e-6f};
                const f32x2 m01 = __builtin_elementwise_max(d01, eps);
                const f32x2 m23 = __builtin_elementwise_max(d23, eps);
                const f32x2 r01 = {__builtin_amdgcn_rcpf(m01[0]), __builtin_amdgcn_rcpf(m01[1])};
                const f32x2 r23 = {__builtin_amdgcn_rcpf(m23[0]), __builtin_amdgcn_rcpf(m23[1])};
                const f32x2 n01 = {S0[qq], S1[qq]};
                const f32x2 n23 = {S2[qq], S3[qq]};
                const f32x2 sc = {0.03125f, 0.03125f};
                const f32x2 a01 = (n01 * r01) * sc;
                const f32x2 a23 = (n23 * r23) * sc;
                const fp16x2 c0 = __builtin_amdgcn_cvt_pkrtz(a01[0], a01[1]);
                const fp16x2 c1 = __builtin_amdgcn_cvt_pkrtz(a23[0], a23[1]);
                pk[kr][0] = __builtin_bit_cast(unsigned, c0);
                pk[kr][1] = __builtin_bit_cast(unsigned, c1);
            }
        }

        // lane-reg transpose: sacc C-layout -> PV A-frag layout, in-register.
        // value k-bits (kr1 kr0 fg1 fg0 h): src regs (kr1 kr0 h), lanes (fg1 fg0)
        //                               -> dst regs (kr1 fg0 h), lanes (kr0 fg1)
        // step1 permlane32_swap: reg-bit kr0 <-> lane-bit5 (fg1)
        // step2 permlane16_swap: reg-bit fg1 <-> lane-bit4 (fg0)
        #pragma unroll
        for (int g = 0; g < 2; ++g)
            #pragma unroll
            for (int hh = 0; hh < 2; ++hh) {
                permlane32_swap(pk[g * 2 + 0][hh], pk[g * 2 + 1][hh]);
                permlane16_swap(pk[g * 2 + 0][hh], pk[g * 2 + 1][hh]);
            }

        // Y += att @ V
        #pragma unroll
        for (int kc = 0; kc < 2; ++kc) {
            const uint4v u = {pk[2 * kc][0], pk[2 * kc][1],
                              pk[2 * kc + 1][0], pk[2 * kc + 1][1]};
            const half8 af = __builtin_bit_cast(half8, u);
            #pragma unroll
            for (int ct = 0; ct < 4; ++ct)
                yacc[ct] = __builtin_amdgcn_mfma_f32_16x16x32_f16(af, vf[ct][kc], yacc[ct], 0, 0, 0);
        }
    }

    // epilogue: ylin f16 = y * 2^-12 (acc holds y*2^-5 -> scale 2^-7)
    #pragma unroll
    for (int ct = 0; ct < 4; ++ct)
        #pragma unroll
        for (int r = 0; r < 4; ++r) {
            const int t = qt * 64 + wv * 16 + fg * 4 + r;
            ylin[(size_t)t * C_DIM + h * HD + ct * 16 + fm] =
                (_Float16)(yacc[ct][r] * 0.0078125f);
        }
}

// ---------------------------------------------------------------------------
// Proj GEMM via f16 MFMA: ylin(f16, *2^-12)[4096,768] @ Wp[768,768] -> out fp32
// ---------------------------------------------------------------------------
__global__ __launch_bounds__(256) void gemm_proj_kernel(
    const _Float16* __restrict__ A, const float* __restrict__ W,
    const float* __restrict__ bias, float* __restrict__ out)
{
    __shared__ _Float16 As[64][72];   // [m][k]
    __shared__ _Float16 Bt[64][72];   // [n][k]
    const int tid = threadIdx.x;
    const int w = tid >> 6, lane = tid & 63;
    const int m = lane & 15, g = lane >> 4;
    const int row0 = blockIdx.x << 6, col0 = blockIdx.y << 6;
    const int ar = tid >> 3, ac8 = (tid & 7) << 3;
    const int bn0 = (tid & 15) << 2, bpv = tid >> 4;
    f32x4 acc[4];
    #pragma unroll
    for (int ct = 0; ct < 4; ++ct) acc[ct] = (f32x4){0.f, 0.f, 0.f, 0.f};

    for (int kt = 0; kt < C_DIM; kt += 64) {
        half8 av0 = *(const half8*)(A + (size_t)(row0 + ar)      * C_DIM + kt + ac8);
        half8 av1 = *(const half8*)(A + (size_t)(row0 + ar + 32) * C_DIM + kt + ac8);
        float4 w0[2], w1[2];
        #pragma unroll
        for (int i = 0; i < 2; ++i) {
            const int k = kt + 2 * (bpv + 16 * i);
            w0[i] = *(const float4*)(W + (size_t)k       * C_DIM + col0 + bn0);
            w1[i] = *(const float4*)(W + (size_t)(k + 1) * C_DIM + col0 + bn0);
        }
        __syncthreads();
        *(half8*)&As[ar][ac8]      = av0;
        *(half8*)&As[ar + 32][ac8] = av1;
        #pragma unroll
        for (int i = 0; i < 2; ++i) {
            const int p = bpv + 16 * i;
            const float a_[4] = {w0[i].x, w0[i].y, w0[i].z, w0[i].w};
            const float b_[4] = {w1[i].x, w1[i].y, w1[i].z, w1[i].w};
            #pragma unroll
            for (int u = 0; u < 4; ++u) {
                half2v pk = {(_Float16)a_[u], (_Float16)b_[u]};
                *(half2v*)&Bt[bn0 + u][2 * p] = pk;
            }
        }
        __syncthreads();
        #pragma unroll
        for (int kc = 0; kc < 2; ++kc) {
            const half8 a = *(half8*)&As[w * 16 + m][kc * 32 + g * 8];
            #pragma unroll
            for (int ct = 0; ct < 4; ++ct) {
                const half8 b = *(half8*)&Bt[ct * 16 + m][kc * 32 + g * 8];
                acc[ct] = __builtin_amdgcn_mfma_f32_16x16x32_f16(a, b, acc[ct], 0, 0, 0);
            }
        }
    }
    #pragma unroll
    for (int ct = 0; ct < 4; ++ct)
        #pragma unroll
        for (int r = 0; r < 4; ++r) {
            const int t = row0 + w * 16 + g * 4 + r;
            const int n = col0 + ct * 16 + m;
            out[(size_t)t * C_DIM + n] = acc[ct][r] * 4096.0f + bias[n];
        }
}

extern "C" void kernel_launch(void* const* d_in, const int* in_sizes, int n_in,
                              void* d_out, int out_size, void* d_ws, size_t ws_size,
                              hipStream_t stream)
{
    const float* x      = (const float*)d_in[0];
    const float* w_attn = (const float*)d_in[1];
    const float* b_attn = (const float*)d_in[2];
    const float* w_proj = (const float*)d_in[3];
    const float* b_proj = (const float*)d_in[4];
    float* out = (float*)d_out;

    const size_t perQK = (size_t)H_NUM * HT;      // 3,145,728
    const size_t perX  = (size_t)T_SEQ * C_DIM;   // 3,145,728
    const size_t perW  = (size_t)N_QKV * C_DIM;   // 1,769,472
    _Float16* base = (_Float16*)d_ws;
    _Float16* xhi  = base;
    _Float16* xlo  = xhi + perX;
    _Float16* wthi = xlo + perX;
    _Float16* wtlo = wthi + perW;
    _Float16* qhi  = wtlo + perW;
    _Float16* qlo  = qhi + perQK;
    _Float16* khi  = qlo + perQK;
    _Float16* klo  = khi + perQK;
    _Float16* vtp  = klo + perQK;
    _Float16* ylin = xhi;                          // reuse: xhi dead after qkv

    split_x_kernel<<<(perX / 4 + 255) / 256, 256, 0, stream>>>(x, xhi, xlo, perX / 4);
    split_wt_kernel<<<dim3(N_QKV / 64, C_DIM / 64), 256, 0, stream>>>(w_attn, wthi, wtlo);
    gemm_qkv_kernel<<<dim3(N_QKV / 64, T_SEQ / 128), 256, 0, stream>>>(
        xhi, xlo, wthi, wtlo, b_attn, qhi, qlo, khi, klo, vtp);
    attn_kernel<<<dim3(T_SEQ / 64, H_NUM), 256, 0, stream>>>(
        qhi, qlo, khi, klo, vtp, ylin);
    gemm_proj_kernel<<<dim3(T_SEQ / 64, C_DIM / 64), 256, 0, stream>>>(
        ylin, w_proj, b_proj, out);
}